// Round 13
// baseline (62.061 us; speedup 1.0000x reference)
//
#include <hip/hip_runtime.h>
#include <hip/hip_bf16.h>
#include <math.h>

#define BB 4
#define CC 64
#define HH 128
#define WW 128
#define NPT 9
#define HW (HH*WW)
#define HP 130
#define WP 130

typedef __attribute__((ext_vector_type(8))) short bf16x8;
typedef __attribute__((ext_vector_type(4))) float f32x4;

static __device__ __forceinline__ unsigned short f2bf(float f) {
    __hip_bfloat16 h = __float2bfloat16(f);
    return *reinterpret_cast<unsigned short*>(&h);
}
static __device__ __forceinline__ float bf2f(unsigned short u) {
    return __uint_as_float(((unsigned int)u) << 16);
}

// ---------------- kernel 0: NHWC transpose (blocks 0..511) + all prep (blocks 512+) ------
// prep flat i: [0,36864) wtt frag-major | [36864,55296) wttB | [55296,55328) b27 | pad-zero
__global__ __launch_bounds__(256) void k_pre(
    const float* __restrict__ x, const float* __restrict__ cw,
    const float* __restrict__ pw, const float* __restrict__ pb,
    const float* __restrict__ mw, const float* __restrict__ mb,
    unsigned short* __restrict__ xt, unsigned short* __restrict__ wtt,
    unsigned short* __restrict__ wttB, float* __restrict__ b27)
{
    __shared__ float tile[64][132];        // stride 132: 16B-aligned rows for b128 LDS ops
    int bid = blockIdx.x;
    int t = threadIdx.x;
    if (bid < BB * HH) {
        int b = bid >> 7, h = bid & 127;
        const float* xb = x + ((size_t)b * CC) * HW + h * WW;
        #pragma unroll
        for (int i = 0; i < 8; ++i) {
            int idx = i * 256 + t;             // 2048 float4 over 64ci x 32 w4
            int ci = idx >> 5, w4 = idx & 31;
            float4 v = *reinterpret_cast<const float4*>(xb + (size_t)ci * HW + w4 * 4);
            *reinterpret_cast<float4*>(&tile[ci][w4 * 4]) = v;
        }
        __syncthreads();
        unsigned short* xtb = xt + (((size_t)b * HP + (h + 1)) * WP + 1) * 64;
        #pragma unroll
        for (int i = 0; i < 4; ++i) {
            int idx = i * 256 + t;             // 1024 items: w(128) x cig(8)
            int w = idx >> 3, cig = idx & 7;
            unsigned int pk[4];
            #pragma unroll
            for (int k = 0; k < 4; ++k) {
                unsigned int u0 = f2bf(tile[cig * 8 + 2 * k][w]);
                unsigned int u1 = f2bf(tile[cig * 8 + 2 * k + 1][w]);
                pk[k] = u0 | (u1 << 16);
            }
            *reinterpret_cast<int4*>(xtb + (size_t)w * 64 + cig * 8) =
                *reinterpret_cast<int4*>(&pk[0]);
        }
        return;
    }
    int i = (bid - BB * HH) * 256 + t;
    if (i < 36864) {
        int cot = i / 9216;
        int rem = i - cot * 9216;
        int n   = rem >> 10;
        int s2  = (rem >> 9) & 1;
        int lhi = (rem >> 7) & 3;
        int l15 = (rem >> 3) & 15;
        int j   = i & 7;
        int co = cot * 16 + l15;
        int ci = s2 * 32 + lhi * 8 + j;
        wtt[i] = f2bf(cw[(co * 64 + ci) * 9 + n]);
    } else if (i < 55296) {
        int q = i - 36864;
        int j   = q & 7;
        int co  = (q >> 3) & 31;
        int lhi = (q >> 8) & 3;
        int s2  = (q >> 10) & 1;
        int n   = q >> 11;
        int ci  = s2 * 32 + lhi * 8 + j;
        float v = 0.f;
        if (co < 18) v = pw[(co * 64 + ci) * 9 + n];
        else if (co < 27) v = mw[((co - 18) * 64 + ci) * 9 + n];
        wttB[q] = f2bf(v);
    } else if (i < 55328) {
        int co = i - 55296;
        b27[co] = (co < 18) ? pb[co] : (co < 27 ? mb[co - 18] : 0.f);
    } else if (i < 55328 + BB * 4128) {
        int p = i - 55328;
        int b = p / 4128, r = p - b * 4128;
        size_t base;
        if (r < 2080) {
            int row = r / 1040;
            int rr  = r - row * 1040;
            int wp = rr >> 3, c8 = rr & 7;
            int hp = row ? (HP - 1) : 0;
            base = (((size_t)b * HP + hp) * WP + wp) * 64 + c8 * 8;
        } else {
            int r2 = r - 2080;
            int col = r2 >> 10;
            int rr  = r2 & 1023;
            int hp = (rr >> 3) + 1, c8 = rr & 7;
            int wp = col ? (WP - 1) : 0;
            base = (((size_t)b * HP + hp) * WP + wp) * 64 + c8 * 8;
        }
        *reinterpret_cast<int4*>(xt + base) = make_int4(0, 0, 0, 0);
    }
}

// ---------------- fused kernel ----------------
// block: 64 px (half h-row) x 64 co out, 256 threads = 4 independent waves.
// wave wid = px-group (16 px); phase D is barrier-free: each wave gathers its own
// A-fragments in-register (lane = (px=ln15, ci-chunk=lhi)) and MFMAs against all 64 co.
#define OMS 68    // s_om row stride (floats)
#define NCX 198   // 3 rows x 66 cols of A-stage chunks

union SmemU {
    unsigned short astage[NCX * 64];                 // 25344 B (phase S/A)
    struct {
        int geo[576 * 8];                            // 18432 B (phase G/D, read-only in D)
        float om[27 * OMS];                          // 7344 B  (phase A->G)
    } d;                                             // 25776 B total
};

__global__ __launch_bounds__(256, 4) void k_fused(
    const unsigned short* __restrict__ xt, const unsigned short* __restrict__ wttB,
    const float* __restrict__ b27, const unsigned short* __restrict__ wtt,
    float* __restrict__ out)
{
    __shared__ SmemU su;

    // XCD-chunked swizzle: 1024 blocks, 8 XCDs
    int blk0 = blockIdx.x;
    int blk = (blk0 & 7) * 128 + (blk0 >> 3);
    int wblk = blk & 1;
    int h = (blk >> 1) & 127;
    int b = blk >> 8;
    int w0 = wblk * 64;
    int t = threadIdx.x;
    int ln = t & 63, wid = t >> 6;          // 4 waves; wid = px-group
    int ln15 = ln & 15, lhi = ln >> 4;

    const unsigned short* xtb = xt + (size_t)b * HP * WP * 64;
    char* astage_c = reinterpret_cast<char*>(su.astage);
    float* s_om = su.d.om;

    // ---- phase S: stage A-tile rows h..h+2, cols w0..w0+65, swizzled ----
    for (int uu = t; uu < NCX * 8; uu += 256) {
        int cx = uu >> 3, o16 = uu & 7;
        int r = cx / 66, c = cx - r * 66;
        const unsigned short* src = xtb + ((size_t)(h + r) * WP + (w0 + c)) * 64 + o16 * 8;
        int4 v = *reinterpret_cast<const int4*>(src);
        *reinterpret_cast<int4*>(astage_c + cx * 128 + ((o16 ^ (cx & 7)) << 4)) = v;
    }
    __syncthreads();

    // ---- phase A: offset/mask conv via MFMA; wave = 16 px x 32 co (2 halves) ----
    {
        int px = wid * 16 + ln15;
        f32x4 a0, a1;
        a0[0] = 0.f; a0[1] = 0.f; a0[2] = 0.f; a0[3] = 0.f;
        a1 = a0;
        #pragma unroll
        for (int ns = 0; ns < 18; ++ns) {
            int n = ns >> 1, s2 = ns & 1;
            int kh = n / 3, kw = n - kh * 3;
            int cx = kh * 66 + px + kw;
            int o16 = s2 * 4 + lhi;
            bf16x8 af = *reinterpret_cast<const bf16x8*>(
                astage_c + cx * 128 + ((o16 ^ (cx & 7)) << 4));
            bf16x8 b0 = *reinterpret_cast<const bf16x8*>(
                wttB + ((size_t)(ns * 4 + lhi) * 32 + ln15) * 8);
            bf16x8 b1 = *reinterpret_cast<const bf16x8*>(
                wttB + ((size_t)(ns * 4 + lhi) * 32 + 16 + ln15) * 8);
            a0 = __builtin_amdgcn_mfma_f32_16x16x32_bf16(af, b0, a0, 0, 0, 0);
            a1 = __builtin_amdgcn_mfma_f32_16x16x32_bf16(af, b1, a1, 0, 0, 0);
        }
        // all astage reads complete before s_om (aliasing) writes
        __syncthreads();
        int prow = wid * 16 + lhi * 4;
        {   // co-half 0: co = ln15 (0..15), always offsets
            float bias = b27[ln15];
            float4 v;
            v.x = a0[0] + bias; v.y = a0[1] + bias;
            v.z = a0[2] + bias; v.w = a0[3] + bias;
            *reinterpret_cast<float4*>(&s_om[ln15 * OMS + prow]) = v;
        }
        {   // co-half 1: co = 16+ln15 (16..31)
            int co = 16 + ln15;
            if (co < 27) {
                float bias = b27[co];
                float4 v;
                v.x = a1[0] + bias; v.y = a1[1] + bias;
                v.z = a1[2] + bias; v.w = a1[3] + bias;
                if (co >= 18) {
                    v.x = 1.f / (1.f + expf(-v.x));
                    v.y = 1.f / (1.f + expf(-v.y));
                    v.z = 1.f / (1.f + expf(-v.z));
                    v.w = 1.f / (1.f + expf(-v.w));
                }
                *reinterpret_cast<float4*>(&s_om[co * OMS + prow]) = v;
            }
        }
    }
    __syncthreads();

    int* s_geo = su.d.geo;

    // ---- phase G: geometry for 9 n x 64 px; layout [float4 w][int4 addr] ----
    for (int idx = t; idx < NPT * 64; idx += 256) {
        int n = idx >> 6, px = idx & 63;
        float ox = s_om[n * OMS + px];
        float oy = s_om[(9 + n) * OMS + px];
        float mk = s_om[(18 + n) * OMS + px];
        float pxf = ox + (float)(n / 3 - 1) + (float)(h + 1);
        float pyf = oy + (float)(n % 3 - 1) + (float)(w0 + px + 1);
        float fx = floorf(pxf), fy = floorf(pyf);
        int qxlt = (int)fminf(fmaxf(fx, 0.f), 129.f);
        int qylt = (int)fminf(fmaxf(fy, 0.f), 129.f);
        int qxrb = (int)fminf(fmaxf(fx + 1.f, 0.f), 129.f);
        int qyrb = (int)fminf(fmaxf(fy + 1.f, 0.f), 129.f);
        float pxc = fminf(fmaxf(pxf, 0.f), 129.f);
        float pyc = fminf(fmaxf(pyf, 0.f), 129.f);
        float ax = 1.f + (float)qxlt - pxc;
        float bx = 1.f - ((float)qxrb - pxc);
        float ay = 1.f + (float)qylt - pyc;
        float by = 1.f - ((float)qyrb - pyc);
        int* g = &s_geo[idx * 8];
        float4 wv;
        wv.x = ax * ay * mk;   // lt
        wv.y = bx * by * mk;   // rb
        wv.z = ax * by * mk;   // lb
        wv.w = bx * ay * mk;   // rt
        int4 av;
        av.x = (qxlt * WP + qylt) * 64;
        av.y = (qxrb * WP + qyrb) * 64;
        av.z = (qxlt * WP + qyrb) * 64;
        av.w = (qxrb * WP + qylt) * 64;
        *reinterpret_cast<float4*>(g) = wv;
        *reinterpret_cast<int4*>(g + 4) = av;
    }
    __syncthreads();
    // s_geo is read-only below; no further barriers needed — waves run free.

    // ---- phase D: per-wave gather -> in-register A-frags -> MFMA vs all 64 co ----
    f32x4 acc[4];
    #pragma unroll
    for (int g = 0; g < 4; ++g) {
        acc[g][0] = 0.f; acc[g][1] = 0.f; acc[g][2] = 0.f; acc[g][3] = 0.f;
    }

    int c0off = lhi * 8;          // ci chunk for s2=0
    int c1off = 32 + lhi * 8;     // ci chunk for s2=1
    const int* mygeo = &s_geo[(wid * 16 + ln15) * 8];

    for (int n = 0; n < NPT; ++n) {
        const float4 wv = *reinterpret_cast<const float4*>(mygeo + n * 512);
        const int4  av = *reinterpret_cast<const int4*>(mygeo + n * 512 + 4);

        // 8 corner-vector gathers (4 corners x 2 ci-halves), all issued up front
        bf16x8 c00 = *reinterpret_cast<const bf16x8*>(xtb + av.x + c0off);
        bf16x8 c10 = *reinterpret_cast<const bf16x8*>(xtb + av.y + c0off);
        bf16x8 c20 = *reinterpret_cast<const bf16x8*>(xtb + av.z + c0off);
        bf16x8 c30 = *reinterpret_cast<const bf16x8*>(xtb + av.w + c0off);
        bf16x8 c01 = *reinterpret_cast<const bf16x8*>(xtb + av.x + c1off);
        bf16x8 c11 = *reinterpret_cast<const bf16x8*>(xtb + av.y + c1off);
        bf16x8 c21 = *reinterpret_cast<const bf16x8*>(xtb + av.z + c1off);
        bf16x8 c31 = *reinterpret_cast<const bf16x8*>(xtb + av.w + c1off);

        unsigned int p0[4], p1[4];
        #pragma unroll
        for (int i = 0; i < 4; ++i) {
            float va0 = wv.x * bf2f((unsigned short)c00[2*i])   + wv.y * bf2f((unsigned short)c10[2*i])
                      + wv.z * bf2f((unsigned short)c20[2*i])   + wv.w * bf2f((unsigned short)c30[2*i]);
            float vb0 = wv.x * bf2f((unsigned short)c00[2*i+1]) + wv.y * bf2f((unsigned short)c10[2*i+1])
                      + wv.z * bf2f((unsigned short)c20[2*i+1]) + wv.w * bf2f((unsigned short)c30[2*i+1]);
            p0[i] = __builtin_amdgcn_perm(__float_as_uint(vb0), __float_as_uint(va0), 0x07060302u);
            float va1 = wv.x * bf2f((unsigned short)c01[2*i])   + wv.y * bf2f((unsigned short)c11[2*i])
                      + wv.z * bf2f((unsigned short)c21[2*i])   + wv.w * bf2f((unsigned short)c31[2*i]);
            float vb1 = wv.x * bf2f((unsigned short)c01[2*i+1]) + wv.y * bf2f((unsigned short)c11[2*i+1])
                      + wv.z * bf2f((unsigned short)c21[2*i+1]) + wv.w * bf2f((unsigned short)c31[2*i+1]);
            p1[i] = __builtin_amdgcn_perm(__float_as_uint(vb1), __float_as_uint(va1), 0x07060302u);
        }
        bf16x8 af0 = *reinterpret_cast<bf16x8*>(&p0[0]);
        bf16x8 af1 = *reinterpret_cast<bf16x8*>(&p1[0]);

        #pragma unroll
        for (int cot = 0; cot < 4; ++cot) {
            bf16x8 bf0 = *reinterpret_cast<const bf16x8*>(
                wtt + (size_t)cot * 9216 + n * 1024 + lhi * 128 + ln15 * 8);
            bf16x8 bf1 = *reinterpret_cast<const bf16x8*>(
                wtt + (size_t)cot * 9216 + n * 1024 + 512 + lhi * 128 + ln15 * 8);
            acc[cot] = __builtin_amdgcn_mfma_f32_16x16x32_bf16(af0, bf0, acc[cot], 0, 0, 0);
            acc[cot] = __builtin_amdgcn_mfma_f32_16x16x32_bf16(af1, bf1, acc[cot], 0, 0, 0);
        }
    }

    // ---- epilogue: lane holds co = cot*16+ln15 (col), px rows = wid*16 + lhi*4 + r ----
    #pragma unroll
    for (int cot = 0; cot < 4; ++cot) {
        int co = cot * 16 + ln15;
        float* orow = out + ((size_t)b * CC + co) * HW + h * WW + w0;
        *reinterpret_cast<float4*>(orow + wid * 16 + lhi * 4) =
            *reinterpret_cast<float4*>(&acc[cot]);
    }
}

extern "C" void kernel_launch(void* const* d_in, const int* in_sizes, int n_in,
                              void* d_out, int out_size, void* d_ws, size_t ws_size,
                              hipStream_t stream) {
    const float* x  = (const float*)d_in[0];
    const float* pw = (const float*)d_in[1];
    const float* pb = (const float*)d_in[2];
    const float* mw = (const float*)d_in[3];
    const float* mb = (const float*)d_in[4];
    const float* cw = (const float*)d_in[5];
    float* out = (float*)d_out;

    char* wsc = (char*)d_ws;
    unsigned short* xt  = (unsigned short*)wsc;                         // 4*130*130*64 bf16
    size_t off = ((size_t)BB * HP * WP * 64 * 2 + 255) & ~(size_t)255;
    unsigned short* wtt = (unsigned short*)(wsc + off);                 // 36864 bf16, frag-major
    off += (size_t)64 * 576 * 2;
    unsigned short* wttB = (unsigned short*)(wsc + off);                // 18432 bf16
    off += (size_t)18432 * 2;
    float* b27 = (float*)(wsc + ((off + 255) & ~(size_t)255));          // 32 f32

    int prep_items = 36864 + 18432 + 32 + BB * 4128;
    int prep_blocks = (prep_items + 255) / 256;
    hipLaunchKernelGGL(k_pre, dim3(BB * HH + prep_blocks), dim3(256), 0, stream,
                       x, cw, pw, pb, mw, mb, xt, wtt, wttB, b27);
    hipLaunchKernelGGL(k_fused, dim3(BB * HH * 2), dim3(256), 0, stream,
                       xt, wttB, b27, wtt, out);
}

// Round 14
// 41.944 us; speedup vs baseline: 1.4796x; 1.4796x over previous
//
#include <hip/hip_runtime.h>
#include <hip/hip_bf16.h>
#include <math.h>

#define BB 4
#define CC 64
#define HH 128
#define WW 128
#define NPT 9
#define HW (HH*WW)
#define HP 130
#define WP 130

typedef __attribute__((ext_vector_type(8))) short bf16x8;
typedef __attribute__((ext_vector_type(4))) float f32x4;
typedef __attribute__((ext_vector_type(2))) float f32x2;

static __device__ __forceinline__ unsigned short f2bf(float f) {
    __hip_bfloat16 h = __float2bfloat16(f);
    return *reinterpret_cast<unsigned short*>(&h);
}
static __device__ __forceinline__ float bf2f(unsigned short u) {
    return __uint_as_float(((unsigned int)u) << 16);
}
// unpack a uint holding 2 bf16 (lo=elem2k, hi=elem2k+1) into f32x2
static __device__ __forceinline__ f32x2 bfpair(unsigned int u) {
    f32x2 r;
    r[0] = __uint_as_float(u << 16);
    r[1] = __uint_as_float(u & 0xffff0000u);
    return r;
}

// ---------------- kernel 0: NHWC transpose (blocks 0..511) + all prep (blocks 512+) ------
// prep flat i: [0,36864) wtt frag-major | [36864,55296) wttB | [55296,55328) b27 | pad-zero
__global__ __launch_bounds__(256) void k_pre(
    const float* __restrict__ x, const float* __restrict__ cw,
    const float* __restrict__ pw, const float* __restrict__ pb,
    const float* __restrict__ mw, const float* __restrict__ mb,
    unsigned short* __restrict__ xt, unsigned short* __restrict__ wtt,
    unsigned short* __restrict__ wttB, float* __restrict__ b27)
{
    __shared__ float tile[64][132];        // stride 132: 16B-aligned rows for b128 LDS ops
    int bid = blockIdx.x;
    int t = threadIdx.x;
    if (bid < BB * HH) {
        int b = bid >> 7, h = bid & 127;
        const float* xb = x + ((size_t)b * CC) * HW + h * WW;
        #pragma unroll
        for (int i = 0; i < 8; ++i) {
            int idx = i * 256 + t;             // 2048 float4 over 64ci x 32 w4
            int ci = idx >> 5, w4 = idx & 31;
            float4 v = *reinterpret_cast<const float4*>(xb + (size_t)ci * HW + w4 * 4);
            *reinterpret_cast<float4*>(&tile[ci][w4 * 4]) = v;
        }
        __syncthreads();
        unsigned short* xtb = xt + (((size_t)b * HP + (h + 1)) * WP + 1) * 64;
        #pragma unroll
        for (int i = 0; i < 4; ++i) {
            int idx = i * 256 + t;             // 1024 items: w(128) x cig(8)
            int w = idx >> 3, cig = idx & 7;
            unsigned int pk[4];
            #pragma unroll
            for (int k = 0; k < 4; ++k) {
                unsigned int u0 = f2bf(tile[cig * 8 + 2 * k][w]);
                unsigned int u1 = f2bf(tile[cig * 8 + 2 * k + 1][w]);
                pk[k] = u0 | (u1 << 16);
            }
            *reinterpret_cast<int4*>(xtb + (size_t)w * 64 + cig * 8) =
                *reinterpret_cast<int4*>(&pk[0]);
        }
        return;
    }
    int i = (bid - BB * HH) * 256 + t;
    if (i < 36864) {
        int cot = i / 9216;
        int rem = i - cot * 9216;
        int n   = rem >> 10;
        int s2  = (rem >> 9) & 1;
        int lhi = (rem >> 7) & 3;
        int l15 = (rem >> 3) & 15;
        int j   = i & 7;
        int co = cot * 16 + l15;
        int ci = s2 * 32 + lhi * 8 + j;
        wtt[i] = f2bf(cw[(co * 64 + ci) * 9 + n]);
    } else if (i < 55296) {
        int q = i - 36864;
        int j   = q & 7;
        int co  = (q >> 3) & 31;
        int lhi = (q >> 8) & 3;
        int s2  = (q >> 10) & 1;
        int n   = q >> 11;
        int ci  = s2 * 32 + lhi * 8 + j;
        float v = 0.f;
        if (co < 18) v = pw[(co * 64 + ci) * 9 + n];
        else if (co < 27) v = mw[((co - 18) * 64 + ci) * 9 + n];
        wttB[q] = f2bf(v);
    } else if (i < 55328) {
        int co = i - 55296;
        b27[co] = (co < 18) ? pb[co] : (co < 27 ? mb[co - 18] : 0.f);
    } else if (i < 55328 + BB * 4128) {
        int p = i - 55328;
        int b = p / 4128, r = p - b * 4128;
        size_t base;
        if (r < 2080) {
            int row = r / 1040;
            int rr  = r - row * 1040;
            int wp = rr >> 3, c8 = rr & 7;
            int hp = row ? (HP - 1) : 0;
            base = (((size_t)b * HP + hp) * WP + wp) * 64 + c8 * 8;
        } else {
            int r2 = r - 2080;
            int col = r2 >> 10;
            int rr  = r2 & 1023;
            int hp = (rr >> 3) + 1, c8 = rr & 7;
            int wp = col ? (WP - 1) : 0;
            base = (((size_t)b * HP + hp) * WP + wp) * 64 + c8 * 8;
        }
        *reinterpret_cast<int4*>(xt + base) = make_int4(0, 0, 0, 0);
    }
}

// ---------------- fused kernel ----------------
// block: 64 px (half h-row) x 64 co out, 512 threads (8 waves).
#define OMS 68    // s_om row stride (floats)
#define NCX 198   // 3 rows x 66 cols of A-stage chunks

// LDS overlay (34816 B total):
//   phase S/A : astage (25344)            [s_om write happens AFTER a barrier ending astage reads]
//   phase A->G: s_om (7344, aliases bytes 18432..25776)
//   phase G->D: geo (18432, bytes 0..18432)
//   phase D   : xoff[2] (16384, aliases s_om region; first write after G's barrier)
union SmemU {
    unsigned short astage[NCX * 64];                 // 25344 B
    struct {
        int geo[576 * 8];                            // 18432 B
        union {
            float om[27 * OMS];                      // 7344 B
            unsigned int xoff[2][2048];              // 16384 B
        } u2;
    } d;                                             // 34816 B
};

__global__ __launch_bounds__(512, 4) void k_fused(
    const unsigned short* __restrict__ xt, const unsigned short* __restrict__ wttB,
    const float* __restrict__ b27, const unsigned short* __restrict__ wtt,
    float* __restrict__ out)
{
    __shared__ SmemU su;

    // XCD-chunked swizzle: 1024 blocks, 8 XCDs
    int blk0 = blockIdx.x;
    int blk = (blk0 & 7) * 128 + (blk0 >> 3);
    int wblk = blk & 1;
    int h = (blk >> 1) & 127;
    int b = blk >> 8;
    int w0 = wblk * 64;
    int t = threadIdx.x;
    int ln = t & 63, wid = t >> 6;          // 8 waves
    int ln15 = ln & 15, lhi = ln >> 4;

    const unsigned short* xtb = xt + (size_t)b * HP * WP * 64;
    char* astage_c = reinterpret_cast<char*>(su.astage);
    float* s_om = su.d.u2.om;

    // ---- phase S: stage A-tile rows h..h+2, cols w0..w0+65, swizzled ----
    for (int uu = t; uu < NCX * 8; uu += 512) {
        int cx = uu >> 3, o16 = uu & 7;
        int r = cx / 66, c = cx - r * 66;
        const unsigned short* src = xtb + ((size_t)(h + r) * WP + (w0 + c)) * 64 + o16 * 8;
        int4 v = *reinterpret_cast<const int4*>(src);
        *reinterpret_cast<int4*>(astage_c + cx * 128 + ((o16 ^ (cx & 7)) << 4)) = v;
    }
    __syncthreads();

    // ---- phase A: offset/mask conv via MFMA (A from LDS, B pipelined), -> s_om ----
    {
        int pxg = wid >> 1, coh = wid & 1;     // wave quadrant: 16 px x 16 co
        int px = pxg * 16 + ln15;
        f32x4 acc;
        acc[0] = 0.f; acc[1] = 0.f; acc[2] = 0.f; acc[3] = 0.f;
        const unsigned short* wB = wttB + (size_t)(coh * 16 + ln15) * 8 + lhi * 256;
        bf16x8 bfc = *reinterpret_cast<const bf16x8*>(wB);       // ns = 0
        #pragma unroll
        for (int ns = 0; ns < 18; ++ns) {
            bf16x8 bfn = bfc;
            if (ns < 17)
                bfn = *reinterpret_cast<const bf16x8*>(wB + (size_t)(ns + 1) * 1024);
            int n = ns >> 1, s2 = ns & 1;
            int kh = n / 3, kw = n - kh * 3;
            int cx = kh * 66 + px + kw;
            int o16 = s2 * 4 + lhi;
            bf16x8 af = *reinterpret_cast<const bf16x8*>(
                astage_c + cx * 128 + ((o16 ^ (cx & 7)) << 4));
            acc = __builtin_amdgcn_mfma_f32_16x16x32_bf16(af, bfc, acc, 0, 0, 0);
            bfc = bfn;
        }
        // barrier: all astage reads complete before s_om (aliasing) writes
        __syncthreads();
        int co = coh * 16 + ln15;
        int prow = pxg * 16 + lhi * 4;
        if (co < 27) {
            float bias = b27[co];
            float4 v;
            v.x = acc[0] + bias; v.y = acc[1] + bias;
            v.z = acc[2] + bias; v.w = acc[3] + bias;
            if (co >= 18) {
                v.x = 1.f / (1.f + expf(-v.x));
                v.y = 1.f / (1.f + expf(-v.y));
                v.z = 1.f / (1.f + expf(-v.z));
                v.w = 1.f / (1.f + expf(-v.w));
            }
            *reinterpret_cast<float4*>(&s_om[co * OMS + prow]) = v;
        }
    }
    __syncthreads();

    int* s_geo = su.d.geo;

    // ---- phase G: geometry for 9 n x 64 px; layout [float4 w][int4 addr] ----
    for (int idx = t; idx < NPT * 64; idx += 512) {
        int n = idx >> 6, px = idx & 63;
        float ox = s_om[n * OMS + px];
        float oy = s_om[(9 + n) * OMS + px];
        float mk = s_om[(18 + n) * OMS + px];
        float pxf = ox + (float)(n / 3 - 1) + (float)(h + 1);
        float pyf = oy + (float)(n % 3 - 1) + (float)(w0 + px + 1);
        float fx = floorf(pxf), fy = floorf(pyf);
        int qxlt = (int)fminf(fmaxf(fx, 0.f), 129.f);
        int qylt = (int)fminf(fmaxf(fy, 0.f), 129.f);
        int qxrb = (int)fminf(fmaxf(fx + 1.f, 0.f), 129.f);
        int qyrb = (int)fminf(fmaxf(fy + 1.f, 0.f), 129.f);
        float pxc = fminf(fmaxf(pxf, 0.f), 129.f);
        float pyc = fminf(fmaxf(pyf, 0.f), 129.f);
        float ax = 1.f + (float)qxlt - pxc;
        float bx = 1.f - ((float)qxrb - pxc);
        float ay = 1.f + (float)qylt - pyc;
        float by = 1.f - ((float)qyrb - pyc);
        int* g = &s_geo[idx * 8];
        float4 wv;
        wv.x = ax * ay * mk;   // lt
        wv.y = bx * by * mk;   // rb
        wv.z = ax * by * mk;   // lb
        wv.w = bx * ay * mk;   // rt
        int4 av;
        av.x = (qxlt * WP + qylt) * 64;
        av.y = (qxrb * WP + qyrb) * 64;
        av.z = (qxlt * WP + qyrb) * 64;
        av.w = (qxrb * WP + qylt) * 64;
        *reinterpret_cast<float4*>(g) = wv;
        *reinterpret_cast<int4*>(g + 4) = av;
    }
    __syncthreads();

    // ---- phase D: sampling + GEMM; xoff double-buffered, 1 barrier/n, gathers 2-deep ----
    f32x4 acc[2];
    #pragma unroll
    for (int g = 0; g < 2; ++g) {
        acc[g][0] = 0.f; acc[g][1] = 0.f; acc[g][2] = 0.f; acc[g][3] = 0.f;
    }

    const unsigned short* wbase = wtt + (size_t)(wid & 3) * 9216;   // frag-major
    int px_s = t >> 3;          // sampling: 64 px
    int cig_s = t & 7;          // 8-ci-vec chunk
    int coff = cig_s * 8;
    char* xoff_base = reinterpret_cast<char*>(su.d.u2.xoff);
    int ghalf = wid >> 2;       // px-half for MFMA role
    int wsw = (cig_s * 16) ^ ((px_s & 7) << 4);   // swizzled write offset within row

    bf16x8 ga0, ga1, ga2, ga3, gb0, gb1, gb2, gb3;

#define GATHER(S0, S1, S2, S3, NN) do {                                        \
        const int4 av_ = *reinterpret_cast<const int4*>(                       \
            &s_geo[((NN) * 64 + px_s) * 8] + 4);                               \
        S0 = *reinterpret_cast<const bf16x8*>(xtb + av_.x + coff);             \
        S1 = *reinterpret_cast<const bf16x8*>(xtb + av_.y + coff);             \
        S2 = *reinterpret_cast<const bf16x8*>(xtb + av_.z + coff);             \
        S3 = *reinterpret_cast<const bf16x8*>(xtb + av_.w + coff);             \
    } while (0)

// packed-f32 bilinear combine: per uint-pair, 4 v_pk ops (1 mul + 3 fma)
#define PACK(S0, S1, S2, S3, NN) do {                                          \
        const float4 wv_ = *reinterpret_cast<const float4*>(                   \
            &s_geo[((NN) * 64 + px_s) * 8]);                                   \
        const unsigned int* u0_ = reinterpret_cast<const unsigned int*>(&S0);  \
        const unsigned int* u1_ = reinterpret_cast<const unsigned int*>(&S1);  \
        const unsigned int* u2_ = reinterpret_cast<const unsigned int*>(&S2);  \
        const unsigned int* u3_ = reinterpret_cast<const unsigned int*>(&S3);  \
        unsigned int pk_[4];                                                   \
        _Pragma("unroll")                                                      \
        for (int i_ = 0; i_ < 4; ++i_) {                                       \
            f32x2 a2_ = wv_.x * bfpair(u0_[i_]);                               \
            a2_ += wv_.y * bfpair(u1_[i_]);                                    \
            a2_ += wv_.z * bfpair(u2_[i_]);                                    \
            a2_ += wv_.w * bfpair(u3_[i_]);                                    \
            pk_[i_] = __builtin_amdgcn_perm(__float_as_uint(a2_[1]),           \
                                            __float_as_uint(a2_[0]), 0x07060302u); \
        }                                                                      \
        *reinterpret_cast<int4*>(xoff_base + ((NN) & 1) * 8192 + px_s * 128 + wsw) \
            = *reinterpret_cast<int4*>(&pk_[0]);                               \
    } while (0)

#define MFMA_N(NN) do {                                                        \
        bf16x8 bf0_ = *reinterpret_cast<const bf16x8*>(                        \
            wbase + (NN) * 1024 + lhi * 128 + ln15 * 8);                       \
        bf16x8 bf1_ = *reinterpret_cast<const bf16x8*>(                        \
            wbase + (NN) * 1024 + 512 + lhi * 128 + ln15 * 8);                 \
        char* rbuf_ = xoff_base + ((NN) & 1) * 8192;                           \
        __builtin_amdgcn_s_setprio(1);                                         \
        _Pragma("unroll")                                                      \
        for (int s2_ = 0; s2_ < 2; ++s2_) {                                    \
            bf16x8 bfr_ = s2_ ? bf1_ : bf0_;                                   \
            _Pragma("unroll")                                                  \
            for (int g_ = 0; g_ < 2; ++g_) {                                   \
                int row_ = (ghalf * 2 + g_) * 16 + ln15;                       \
                int cb2_ = (s2_ * 32 + lhi * 8) * 2;                           \
                bf16x8 af_ = *reinterpret_cast<const bf16x8*>(                 \
                    rbuf_ + row_ * 128 + (cb2_ ^ ((row_ & 7) << 4)));          \
                acc[g_] = __builtin_amdgcn_mfma_f32_16x16x32_bf16(             \
                    af_, bfr_, acc[g_], 0, 0, 0);                              \
            }                                                                  \
        }                                                                      \
        __builtin_amdgcn_s_setprio(0);                                         \
    } while (0)

    // prologue: gathers for n=0,1; pack n=0 -> buf0
    GATHER(ga0, ga1, ga2, ga3, 0);
    GATHER(gb0, gb1, gb2, gb3, 1);
    PACK(ga0, ga1, ga2, ga3, 0);
    __syncthreads();

#define DSTEP(NN, N0, N1, N2, N3, P0, P1, P2, P3) do {                         \
        if ((NN) + 2 < NPT) GATHER(N0, N1, N2, N3, (NN) + 2);                  \
        MFMA_N(NN);                                                            \
        if ((NN) + 1 < NPT) {                                                  \
            PACK(P0, P1, P2, P3, (NN) + 1);                                    \
            __syncthreads();                                                   \
        }                                                                      \
    } while (0)

    DSTEP(0, ga0, ga1, ga2, ga3, gb0, gb1, gb2, gb3);
    DSTEP(1, gb0, gb1, gb2, gb3, ga0, ga1, ga2, ga3);
    DSTEP(2, ga0, ga1, ga2, ga3, gb0, gb1, gb2, gb3);
    DSTEP(3, gb0, gb1, gb2, gb3, ga0, ga1, ga2, ga3);
    DSTEP(4, ga0, ga1, ga2, ga3, gb0, gb1, gb2, gb3);
    DSTEP(5, gb0, gb1, gb2, gb3, ga0, ga1, ga2, ga3);
    DSTEP(6, ga0, ga1, ga2, ga3, gb0, gb1, gb2, gb3);
    DSTEP(7, gb0, gb1, gb2, gb3, ga0, ga1, ga2, ga3);
    DSTEP(8, ga0, ga1, ga2, ga3, gb0, gb1, gb2, gb3);

    // ---- epilogue ----
    int co = (wid & 3) * 16 + ln15;
    float* orow = out + ((size_t)b * CC + co) * HW + h * WW + w0;
    #pragma unroll
    for (int g = 0; g < 2; ++g) {
        *reinterpret_cast<float4*>(orow + (ghalf * 2 + g) * 16 + lhi * 4) =
            *reinterpret_cast<float4*>(&acc[g]);
    }
}

extern "C" void kernel_launch(void* const* d_in, const int* in_sizes, int n_in,
                              void* d_out, int out_size, void* d_ws, size_t ws_size,
                              hipStream_t stream) {
    const float* x  = (const float*)d_in[0];
    const float* pw = (const float*)d_in[1];
    const float* pb = (const float*)d_in[2];
    const float* mw = (const float*)d_in[3];
    const float* mb = (const float*)d_in[4];
    const float* cw = (const float*)d_in[5];
    float* out = (float*)d_out;

    char* wsc = (char*)d_ws;
    unsigned short* xt  = (unsigned short*)wsc;                         // 4*130*130*64 bf16
    size_t off = ((size_t)BB * HP * WP * 64 * 2 + 255) & ~(size_t)255;
    unsigned short* wtt = (unsigned short*)(wsc + off);                 // 36864 bf16, frag-major
    off += (size_t)64 * 576 * 2;
    unsigned short* wttB = (unsigned short*)(wsc + off);                // 18432 bf16
    off += (size_t)18432 * 2;
    float* b27 = (float*)(wsc + ((off + 255) & ~(size_t)255));          // 32 f32

    int prep_items = 36864 + 18432 + 32 + BB * 4128;
    int prep_blocks = (prep_items + 255) / 256;
    hipLaunchKernelGGL(k_pre, dim3(BB * HH + prep_blocks), dim3(256), 0, stream,
                       x, cw, pw, pb, mw, mb, xt, wtt, wttB, b27);
    hipLaunchKernelGGL(k_fused, dim3(BB * HH * 2), dim3(512), 0, stream,
                       xt, wttB, b27, wtt, out);
}

// Round 15
// 40.588 us; speedup vs baseline: 1.5291x; 1.0334x over previous
//
#include <hip/hip_runtime.h>
#include <hip/hip_bf16.h>
#include <math.h>

#define BB 4
#define CC 64
#define HH 128
#define WW 128
#define NPT 9
#define HW (HH*WW)
#define HP 130
#define WP 130

typedef __attribute__((ext_vector_type(8))) short bf16x8;
typedef __attribute__((ext_vector_type(4))) float f32x4;

static __device__ __forceinline__ unsigned short f2bf(float f) {
    __hip_bfloat16 h = __float2bfloat16(f);
    return *reinterpret_cast<unsigned short*>(&h);
}
static __device__ __forceinline__ float bf2f(unsigned short u) {
    return __uint_as_float(((unsigned int)u) << 16);
}

// ---------------- kernel 0: NHWC transpose (blocks 0..511) + all prep (blocks 512+) ------
// prep flat i: [0,36864) wtt frag-major | [36864,55296) wttB | [55296,55328) b27 | pad-zero
__global__ __launch_bounds__(256) void k_pre(
    const float* __restrict__ x, const float* __restrict__ cw,
    const float* __restrict__ pw, const float* __restrict__ pb,
    const float* __restrict__ mw, const float* __restrict__ mb,
    unsigned short* __restrict__ xt, unsigned short* __restrict__ wtt,
    unsigned short* __restrict__ wttB, float* __restrict__ b27)
{
    __shared__ float tile[64][132];        // stride 132: 16B-aligned rows for b128 LDS ops
    int bid = blockIdx.x;
    int t = threadIdx.x;
    if (bid < BB * HH) {
        int b = bid >> 7, h = bid & 127;
        const float* xb = x + ((size_t)b * CC) * HW + h * WW;
        #pragma unroll
        for (int i = 0; i < 8; ++i) {
            int idx = i * 256 + t;             // 2048 float4 over 64ci x 32 w4
            int ci = idx >> 5, w4 = idx & 31;
            float4 v = *reinterpret_cast<const float4*>(xb + (size_t)ci * HW + w4 * 4);
            *reinterpret_cast<float4*>(&tile[ci][w4 * 4]) = v;
        }
        __syncthreads();
        unsigned short* xtb = xt + (((size_t)b * HP + (h + 1)) * WP + 1) * 64;
        #pragma unroll
        for (int i = 0; i < 4; ++i) {
            int idx = i * 256 + t;             // 1024 items: w(128) x cig(8)
            int w = idx >> 3, cig = idx & 7;
            unsigned int pk[4];
            #pragma unroll
            for (int k = 0; k < 4; ++k) {
                unsigned int u0 = f2bf(tile[cig * 8 + 2 * k][w]);
                unsigned int u1 = f2bf(tile[cig * 8 + 2 * k + 1][w]);
                pk[k] = u0 | (u1 << 16);
            }
            *reinterpret_cast<int4*>(xtb + (size_t)w * 64 + cig * 8) =
                *reinterpret_cast<int4*>(&pk[0]);
        }
        return;
    }
    int i = (bid - BB * HH) * 256 + t;
    if (i < 36864) {
        int cot = i / 9216;
        int rem = i - cot * 9216;
        int n   = rem >> 10;
        int s2  = (rem >> 9) & 1;
        int lhi = (rem >> 7) & 3;
        int l15 = (rem >> 3) & 15;
        int j   = i & 7;
        int co = cot * 16 + l15;
        int ci = s2 * 32 + lhi * 8 + j;
        wtt[i] = f2bf(cw[(co * 64 + ci) * 9 + n]);
    } else if (i < 55296) {
        int q = i - 36864;
        int j   = q & 7;
        int co  = (q >> 3) & 31;
        int lhi = (q >> 8) & 3;
        int s2  = (q >> 10) & 1;
        int n   = q >> 11;
        int ci  = s2 * 32 + lhi * 8 + j;
        float v = 0.f;
        if (co < 18) v = pw[(co * 64 + ci) * 9 + n];
        else if (co < 27) v = mw[((co - 18) * 64 + ci) * 9 + n];
        wttB[q] = f2bf(v);
    } else if (i < 55328) {
        int co = i - 55296;
        b27[co] = (co < 18) ? pb[co] : (co < 27 ? mb[co - 18] : 0.f);
    } else if (i < 55328 + BB * 4128) {
        int p = i - 55328;
        int b = p / 4128, r = p - b * 4128;
        size_t base;
        if (r < 2080) {
            int row = r / 1040;
            int rr  = r - row * 1040;
            int wp = rr >> 3, c8 = rr & 7;
            int hp = row ? (HP - 1) : 0;
            base = (((size_t)b * HP + hp) * WP + wp) * 64 + c8 * 8;
        } else {
            int r2 = r - 2080;
            int col = r2 >> 10;
            int rr  = r2 & 1023;
            int hp = (rr >> 3) + 1, c8 = rr & 7;
            int wp = col ? (WP - 1) : 0;
            base = (((size_t)b * HP + hp) * WP + wp) * 64 + c8 * 8;
        }
        *reinterpret_cast<int4*>(xt + base) = make_int4(0, 0, 0, 0);
    }
}

// ---------------- fused kernel ----------------
// block: 64 px (half h-row) x 64 co out, 512 threads (8 waves).
#define OMS 68    // s_om row stride (floats)
#define NCX 198   // 3 rows x 66 cols of A-stage chunks

// LDS overlay (34816 B total):
//   phase S/A : astage (25344)            [s_om write happens AFTER a barrier ending astage reads]
//   phase A->G: s_om (7344, aliases bytes 18432..25776)
//   phase G->D: geo (18432, bytes 0..18432)
//   phase D   : xoff[2] (16384, aliases s_om region; first write after G's barrier)
union SmemU {
    unsigned short astage[NCX * 64];                 // 25344 B
    struct {
        int geo[576 * 8];                            // 18432 B
        union {
            float om[27 * OMS];                      // 7344 B
            unsigned int xoff[2][2048];              // 16384 B
        } u2;
    } d;                                             // 34816 B
};

__global__ __launch_bounds__(512, 4) void k_fused(
    const unsigned short* __restrict__ xt, const unsigned short* __restrict__ wttB,
    const float* __restrict__ b27, const unsigned short* __restrict__ wtt,
    float* __restrict__ out)
{
    __shared__ SmemU su;

    // XCD-chunked swizzle: 1024 blocks, 8 XCDs
    int blk0 = blockIdx.x;
    int blk = (blk0 & 7) * 128 + (blk0 >> 3);
    int wblk = blk & 1;
    int h = (blk >> 1) & 127;
    int b = blk >> 8;
    int w0 = wblk * 64;
    int t = threadIdx.x;
    int ln = t & 63, wid = t >> 6;          // 8 waves
    int ln15 = ln & 15, lhi = ln >> 4;

    const unsigned short* xtb = xt + (size_t)b * HP * WP * 64;
    char* astage_c = reinterpret_cast<char*>(su.astage);
    float* s_om = su.d.u2.om;

    // ---- phase S: stage A-tile rows h..h+2, cols w0..w0+65, swizzled ----
    for (int uu = t; uu < NCX * 8; uu += 512) {
        int cx = uu >> 3, o16 = uu & 7;
        int r = cx / 66, c = cx - r * 66;
        const unsigned short* src = xtb + ((size_t)(h + r) * WP + (w0 + c)) * 64 + o16 * 8;
        int4 v = *reinterpret_cast<const int4*>(src);
        *reinterpret_cast<int4*>(astage_c + cx * 128 + ((o16 ^ (cx & 7)) << 4)) = v;
    }
    __syncthreads();

    // ---- phase A: offset/mask conv via MFMA (A from LDS, B pipelined), -> s_om ----
    {
        int pxg = wid >> 1, coh = wid & 1;     // wave quadrant: 16 px x 16 co
        int px = pxg * 16 + ln15;
        f32x4 acc;
        acc[0] = 0.f; acc[1] = 0.f; acc[2] = 0.f; acc[3] = 0.f;
        const unsigned short* wB = wttB + (size_t)(coh * 16 + ln15) * 8 + lhi * 256;
        bf16x8 bfc = *reinterpret_cast<const bf16x8*>(wB);       // ns = 0
        #pragma unroll
        for (int ns = 0; ns < 18; ++ns) {
            bf16x8 bfn = bfc;
            if (ns < 17)
                bfn = *reinterpret_cast<const bf16x8*>(wB + (size_t)(ns + 1) * 1024);
            int n = ns >> 1, s2 = ns & 1;
            int kh = n / 3, kw = n - kh * 3;
            int cx = kh * 66 + px + kw;
            int o16 = s2 * 4 + lhi;
            bf16x8 af = *reinterpret_cast<const bf16x8*>(
                astage_c + cx * 128 + ((o16 ^ (cx & 7)) << 4));
            acc = __builtin_amdgcn_mfma_f32_16x16x32_bf16(af, bfc, acc, 0, 0, 0);
            bfc = bfn;
        }
        // barrier: all astage reads complete before s_om (aliasing) writes
        __syncthreads();
        int co = coh * 16 + ln15;
        int prow = pxg * 16 + lhi * 4;
        if (co < 27) {
            float bias = b27[co];
            float4 v;
            v.x = acc[0] + bias; v.y = acc[1] + bias;
            v.z = acc[2] + bias; v.w = acc[3] + bias;
            if (co >= 18) {
                v.x = 1.f / (1.f + expf(-v.x));
                v.y = 1.f / (1.f + expf(-v.y));
                v.z = 1.f / (1.f + expf(-v.z));
                v.w = 1.f / (1.f + expf(-v.w));
            }
            *reinterpret_cast<float4*>(&s_om[co * OMS + prow]) = v;
        }
    }
    __syncthreads();

    int* s_geo = su.d.geo;

    // ---- phase G: geometry for 9 n x 64 px; layout [float4 w][int4 addr] ----
    for (int idx = t; idx < NPT * 64; idx += 512) {
        int n = idx >> 6, px = idx & 63;
        float ox = s_om[n * OMS + px];
        float oy = s_om[(9 + n) * OMS + px];
        float mk = s_om[(18 + n) * OMS + px];
        float pxf = ox + (float)(n / 3 - 1) + (float)(h + 1);
        float pyf = oy + (float)(n % 3 - 1) + (float)(w0 + px + 1);
        float fx = floorf(pxf), fy = floorf(pyf);
        int qxlt = (int)fminf(fmaxf(fx, 0.f), 129.f);
        int qylt = (int)fminf(fmaxf(fy, 0.f), 129.f);
        int qxrb = (int)fminf(fmaxf(fx + 1.f, 0.f), 129.f);
        int qyrb = (int)fminf(fmaxf(fy + 1.f, 0.f), 129.f);
        float pxc = fminf(fmaxf(pxf, 0.f), 129.f);
        float pyc = fminf(fmaxf(pyf, 0.f), 129.f);
        float ax = 1.f + (float)qxlt - pxc;
        float bx = 1.f - ((float)qxrb - pxc);
        float ay = 1.f + (float)qylt - pyc;
        float by = 1.f - ((float)qyrb - pyc);
        int* g = &s_geo[idx * 8];
        float4 wv;
        wv.x = ax * ay * mk;   // lt
        wv.y = bx * by * mk;   // rb
        wv.z = ax * by * mk;   // lb
        wv.w = bx * ay * mk;   // rt
        int4 av;
        av.x = (qxlt * WP + qylt) * 64;
        av.y = (qxrb * WP + qyrb) * 64;
        av.z = (qxlt * WP + qyrb) * 64;
        av.w = (qxrb * WP + qylt) * 64;
        *reinterpret_cast<float4*>(g) = wv;
        *reinterpret_cast<int4*>(g + 4) = av;
    }
    __syncthreads();

    // ---- phase D: sampling + GEMM; xoff double-buffered, 1 barrier/n, gathers 2-deep ----
    f32x4 acc[2];
    #pragma unroll
    for (int g = 0; g < 2; ++g) {
        acc[g][0] = 0.f; acc[g][1] = 0.f; acc[g][2] = 0.f; acc[g][3] = 0.f;
    }

    const unsigned short* wbase = wtt + (size_t)(wid & 3) * 9216;   // frag-major
    int px_s = t >> 3;          // sampling: 64 px
    int cig_s = t & 7;          // 8-ci-vec chunk
    int coff = cig_s * 8;
    char* xoff_base = reinterpret_cast<char*>(su.d.u2.xoff);
    int ghalf = wid >> 2;       // px-half for MFMA role
    int wsw = (cig_s * 16) ^ ((px_s & 7) << 4);   // swizzled write offset within row

    bf16x8 ga0, ga1, ga2, ga3, gb0, gb1, gb2, gb3;

#define GATHER(S0, S1, S2, S3, NN) do {                                        \
        const int4 av_ = *reinterpret_cast<const int4*>(                       \
            &s_geo[((NN) * 64 + px_s) * 8] + 4);                               \
        S0 = *reinterpret_cast<const bf16x8*>(xtb + av_.x + coff);             \
        S1 = *reinterpret_cast<const bf16x8*>(xtb + av_.y + coff);             \
        S2 = *reinterpret_cast<const bf16x8*>(xtb + av_.z + coff);             \
        S3 = *reinterpret_cast<const bf16x8*>(xtb + av_.w + coff);             \
    } while (0)

#define PACK(S0, S1, S2, S3, NN) do {                                          \
        const float4 wv_ = *reinterpret_cast<const float4*>(                   \
            &s_geo[((NN) * 64 + px_s) * 8]);                                   \
        unsigned int pk_[4];                                                   \
        _Pragma("unroll")                                                      \
        for (int i_ = 0; i_ < 4; ++i_) {                                       \
            float va_ = wv_.x * bf2f((unsigned short)S0[2*i_])                 \
                      + wv_.y * bf2f((unsigned short)S1[2*i_])                 \
                      + wv_.z * bf2f((unsigned short)S2[2*i_])                 \
                      + wv_.w * bf2f((unsigned short)S3[2*i_]);                \
            float vb_ = wv_.x * bf2f((unsigned short)S0[2*i_+1])               \
                      + wv_.y * bf2f((unsigned short)S1[2*i_+1])               \
                      + wv_.z * bf2f((unsigned short)S2[2*i_+1])               \
                      + wv_.w * bf2f((unsigned short)S3[2*i_+1]);              \
            pk_[i_] = __builtin_amdgcn_perm(__float_as_uint(vb_),              \
                                            __float_as_uint(va_), 0x07060302u); \
        }                                                                      \
        *reinterpret_cast<int4*>(xoff_base + ((NN) & 1) * 8192 + px_s * 128 + wsw) \
            = *reinterpret_cast<int4*>(&pk_[0]);                               \
    } while (0)

#define MFMA_N(NN) do {                                                        \
        bf16x8 bf0_ = *reinterpret_cast<const bf16x8*>(                        \
            wbase + (NN) * 1024 + lhi * 128 + ln15 * 8);                       \
        bf16x8 bf1_ = *reinterpret_cast<const bf16x8*>(                        \
            wbase + (NN) * 1024 + 512 + lhi * 128 + ln15 * 8);                 \
        char* rbuf_ = xoff_base + ((NN) & 1) * 8192;                           \
        _Pragma("unroll")                                                      \
        for (int s2_ = 0; s2_ < 2; ++s2_) {                                    \
            bf16x8 bfr_ = s2_ ? bf1_ : bf0_;                                   \
            _Pragma("unroll")                                                  \
            for (int g_ = 0; g_ < 2; ++g_) {                                   \
                int row_ = (ghalf * 2 + g_) * 16 + ln15;                       \
                int cb2_ = (s2_ * 32 + lhi * 8) * 2;                           \
                bf16x8 af_ = *reinterpret_cast<const bf16x8*>(                 \
                    rbuf_ + row_ * 128 + (cb2_ ^ ((row_ & 7) << 4)));          \
                acc[g_] = __builtin_amdgcn_mfma_f32_16x16x32_bf16(             \
                    af_, bfr_, acc[g_], 0, 0, 0);                              \
            }                                                                  \
        }                                                                      \
    } while (0)

    // prologue: gathers for n=0,1; pack n=0 -> buf0
    GATHER(ga0, ga1, ga2, ga3, 0);
    GATHER(gb0, gb1, gb2, gb3, 1);
    PACK(ga0, ga1, ga2, ga3, 0);
    __syncthreads();

#define DSTEP(NN, N0, N1, N2, N3, P0, P1, P2, P3) do {                         \
        if ((NN) + 2 < NPT) GATHER(N0, N1, N2, N3, (NN) + 2);                  \
        MFMA_N(NN);                                                            \
        if ((NN) + 1 < NPT) {                                                  \
            PACK(P0, P1, P2, P3, (NN) + 1);                                    \
            __syncthreads();                                                   \
        }                                                                      \
    } while (0)

    DSTEP(0, ga0, ga1, ga2, ga3, gb0, gb1, gb2, gb3);
    DSTEP(1, gb0, gb1, gb2, gb3, ga0, ga1, ga2, ga3);
    DSTEP(2, ga0, ga1, ga2, ga3, gb0, gb1, gb2, gb3);
    DSTEP(3, gb0, gb1, gb2, gb3, ga0, ga1, ga2, ga3);
    DSTEP(4, ga0, ga1, ga2, ga3, gb0, gb1, gb2, gb3);
    DSTEP(5, gb0, gb1, gb2, gb3, ga0, ga1, ga2, ga3);
    DSTEP(6, ga0, ga1, ga2, ga3, gb0, gb1, gb2, gb3);
    DSTEP(7, gb0, gb1, gb2, gb3, ga0, ga1, ga2, ga3);
    DSTEP(8, ga0, ga1, ga2, ga3, gb0, gb1, gb2, gb3);

    // ---- epilogue ----
    int co = (wid & 3) * 16 + ln15;
    float* orow = out + ((size_t)b * CC + co) * HW + h * WW + w0;
    #pragma unroll
    for (int g = 0; g < 2; ++g) {
        *reinterpret_cast<float4*>(orow + (ghalf * 2 + g) * 16 + lhi * 4) =
            *reinterpret_cast<float4*>(&acc[g]);
    }
}

extern "C" void kernel_launch(void* const* d_in, const int* in_sizes, int n_in,
                              void* d_out, int out_size, void* d_ws, size_t ws_size,
                              hipStream_t stream) {
    const float* x  = (const float*)d_in[0];
    const float* pw = (const float*)d_in[1];
    const float* pb = (const float*)d_in[2];
    const float* mw = (const float*)d_in[3];
    const float* mb = (const float*)d_in[4];
    const float* cw = (const float*)d_in[5];
    float* out = (float*)d_out;

    char* wsc = (char*)d_ws;
    unsigned short* xt  = (unsigned short*)wsc;                         // 4*130*130*64 bf16
    size_t off = ((size_t)BB * HP * WP * 64 * 2 + 255) & ~(size_t)255;
    unsigned short* wtt = (unsigned short*)(wsc + off);                 // 36864 bf16, frag-major
    off += (size_t)64 * 576 * 2;
    unsigned short* wttB = (unsigned short*)(wsc + off);                // 18432 bf16
    off += (size_t)18432 * 2;
    float* b27 = (float*)(wsc + ((off + 255) & ~(size_t)255));          // 32 f32

    int prep_items = 36864 + 18432 + 32 + BB * 4128;
    int prep_blocks = (prep_items + 255) / 256;
    hipLaunchKernelGGL(k_pre, dim3(BB * HH + prep_blocks), dim3(256), 0, stream,
                       x, cw, pw, pb, mw, mb, xt, wtt, wttB, b27);
    hipLaunchKernelGGL(k_fused, dim3(BB * HH * 2), dim3(512), 0, stream,
                       xt, wttB, b27, wtt, out);
}